// Round 10
// baseline (378.495 us; speedup 1.0000x reference)
//
#include <hip/hip_runtime.h>
#include <cmath>

// RoPEAttention: S=4096, D=2048, base=10000
// GEMM core: 256x256 tile, BK=64, 8 waves (2Mx4N), 8-phase schedule with
// counted vmcnt(6), XOR LDS swizzle (pre-swizzled global source + swizzled
// ds_read, linear global_load_lds dest), s_setprio around MFMA, explicit
// lgkmcnt(0) after the pre-MFMA barrier (m201-faithful), NON-TEMPORAL C
// stores (fp32 C stream was write-allocating in L2/L3 and evicting input
// panels: FETCH_SIZE 139MB vs 32MB inputs -> HBM-latency staging stalls).
// fp16 in / fp32 out, mfma_f32_16x16x32_f16. Split-K via gridDim.z.
// Launch plan (all GEMMs round-exact on 256 CUs at 1 block/CU):
//   QK N=4096 -> 256 blocks; V N=2048 split-K=2 -> 256; scores 256; PV 256.
// NOTE: T1 XCD swizzle removed (measured regression, L3-resident set).
// NOTE: round-9 "max-lead" staging REVERTED (regressed 72.5->77us; lead-
// latency theory falsified). NOTE: fused RoPE/V-transpose epilogue abandoned
// (EPI=1 deterministically corrupted results; suspected spill VMEM breaking
// counted-vmcnt discipline).

typedef _Float16 f16;
typedef __attribute__((ext_vector_type(2))) _Float16 f16x2;
typedef __attribute__((ext_vector_type(4))) _Float16 f16x4;
typedef __attribute__((ext_vector_type(8))) _Float16 f16x8;
typedef __attribute__((ext_vector_type(4))) float f32x4;

#define GLD16(g, loff)                                                         \
  __builtin_amdgcn_global_load_lds(                                            \
      (const __attribute__((address_space(1))) void*)(g),                      \
      (__attribute__((address_space(3))) void*)(smem + (loff)), 16, 0, 0)

#define STAGE(BUFOFF, REG, PL0, PL1, KT)                                       \
  do {                                                                         \
    GLD16((PL0) + (KT), (BUFOFF) + (REG) + d0);                                \
    GLD16((PL1) + (KT), (BUFOFF) + (REG) + d1);                                \
  } while (0)

#define BAR() __builtin_amdgcn_s_barrier()
#define WAITLGKM() asm volatile("s_waitcnt lgkmcnt(0)" ::: "memory")
#define WAITVM6() asm volatile("s_waitcnt vmcnt(6)" ::: "memory")
#define WAITVM0() asm volatile("s_waitcnt vmcnt(0)" ::: "memory")

#define LOAD_A(BUF, MQ)                                                        \
  _Pragma("unroll") for (int i = 0; i < 4; ++i) {                              \
    af[i][0] = *(const f16x8*)(smem + (BUF) + rba +                            \
                               (((MQ) * 64 + i * 16) << 7) + kxa0);            \
    af[i][1] = *(const f16x8*)(smem + (BUF) + rba +                            \
                               (((MQ) * 64 + i * 16) << 7) + kxa1);            \
  }

#define LOAD_B(BUF, NQ, BF)                                                    \
  _Pragma("unroll") for (int j = 0; j < 2; ++j) {                              \
    BF[j][0] = *(const f16x8*)(smem + (BUF) + rbb +                            \
                               (((NQ) * 32 + j * 16) << 7) + kxa0);            \
    BF[j][1] = *(const f16x8*)(smem + (BUF) + rbb +                            \
                               (((NQ) * 32 + j * 16) << 7) + kxa1);            \
  }

#define MFMA_Q(MQ, NQ, BF)                                                     \
  __builtin_amdgcn_s_setprio(1);                                               \
  _Pragma("unroll") for (int ks = 0; ks < 2; ++ks)                             \
  _Pragma("unroll") for (int i = 0; i < 4; ++i)                                \
  _Pragma("unroll") for (int j = 0; j < 2; ++j)                                \
    acc[(MQ) * 4 + i][(NQ) * 2 + j] = __builtin_amdgcn_mfma_f32_16x16x32_f16(  \
        af[i][ks], BF[j][ks], acc[(MQ) * 4 + i][(NQ) * 2 + j], 0, 0, 0);       \
  __builtin_amdgcn_s_setprio(0)

// C[M,N] = alpha * A[M,K] @ B[N,K]^T, row stride Kstride for A and B.
// Split-K: blockIdx.z offsets A,B by z*K and C by z*M*N (partials).
// M,N % 256 == 0, K % 128 == 0. grid = (N/256, M/256, splits), block = 512.
__global__ __launch_bounds__(512) void gemm256_8ph(
    const f16* __restrict__ A, const f16* __restrict__ B,
    float* __restrict__ C, int M, int N, int K, int Kstride, float alpha) {
  __shared__ __align__(16) char smem[131072];
  const int tid = threadIdx.x;
  const int wave = tid >> 6, lane = tid & 63;
  const int wm = wave >> 2, wn = wave & 3;  // 2 x 4 wave grid
  const int l15 = lane & 15, kq = lane >> 4;
  const int bm = blockIdx.y << 8, bn = blockIdx.x << 8;

  // split-K offsets (zero when gridDim.z == 1)
  const size_t zofs = (size_t)blockIdx.z * (size_t)K;
  A += zofs;
  B += zofs;
  C += (size_t)blockIdx.z * (size_t)M * N;

  f32x4 acc[8][4];
#pragma unroll
  for (int m = 0; m < 8; ++m)
#pragma unroll
    for (int n = 0; n < 4; ++n) acc[m][n] = f32x4{0.f, 0.f, 0.f, 0.f};

  // staging: half-tile = 1024 16B-chunks; chunk c -> (row=c>>3, slot=c&7);
  // source k8 = slot ^ (row&7)  (swizzle on the SOURCE, LDS dest linear).
  const int c0 = wave * 64 + lane;
  const int c1 = 512 + c0;
  const int r0 = c0 >> 3, q0 = ((c0 & 7) ^ (r0 & 7)) << 3;
  const int r1 = c1 >> 3, q1 = ((c1 & 7) ^ (r1 & 7)) << 3;
  const f16* pa0 = A + (size_t)(bm + r0) * Kstride + q0;        // A half0
  const f16* pa1 = A + (size_t)(bm + r1) * Kstride + q1;
  const f16* pA0 = A + (size_t)(bm + 128 + r0) * Kstride + q0;  // A half1
  const f16* pA1 = A + (size_t)(bm + 128 + r1) * Kstride + q1;
  const f16* pb0 = B + (size_t)(bn + r0) * Kstride + q0;        // B half0
  const f16* pb1 = B + (size_t)(bn + r1) * Kstride + q1;
  const f16* pB0 = B + (size_t)(bn + 128 + r0) * Kstride + q0;  // B half1
  const f16* pB1 = B + (size_t)(bn + 128 + r1) * Kstride + q1;
  const int d0 = wave << 10;
  const int d1 = 8192 + d0;

  // ds_read addressing (XOR swizzle on the read side)
  const int swz = l15 & 7;
  const int kxa0 = (kq ^ swz) << 4;
  const int kxa1 = ((4 + kq) ^ swz) << 4;
  const int rba = (wm * 128 + l15) << 7;
  const int rbb = 32768 + ((wn * 64 + l15) << 7);

  const int nt2 = K >> 7;  // each iteration covers 2 K-tiles of 64

  // prologue: t0 fully, t1 {B0,B1,A0}; vmcnt(6) lands t0.
  STAGE(0, 0, pa0, pa1, 0);
  STAGE(0, 16384, pA0, pA1, 0);
  STAGE(0, 32768, pb0, pb1, 0);
  STAGE(0, 49152, pB0, pB1, 0);
  STAGE(65536, 32768, pb0, pb1, 64);
  STAGE(65536, 49152, pB0, pB1, 64);
  STAGE(65536, 0, pa0, pa1, 64);
  WAITVM6();
  BAR();

  f16x8 af[4][2], bf0[2][2], bf1[2][2];

  for (int it = 0; it < nt2; ++it) {
    const int kt = it << 7;
    const bool full = (it != nt2 - 1);
    // ph1: quadrant (0,0) of tile 2it (buf0); stage t(2it+1):A1
    LOAD_A(0, 0);
    LOAD_B(0, 0, bf0);
    STAGE(65536, 16384, pA0, pA1, kt + 64);
    BAR();
    WAITLGKM();
    MFMA_Q(0, 0, bf0);
    BAR();
    // ph2: (0,1)
    LOAD_B(0, 1, bf1);
    BAR();
    WAITLGKM();
    MFMA_Q(0, 1, bf1);
    BAR();
    // ph3: (1,1); buf0-B dead after ph2 -> stage t+2:B0
    LOAD_A(0, 1);
    if (full) STAGE(0, 32768, pb0, pb1, kt + 128);
    BAR();
    WAITLGKM();
    MFMA_Q(1, 1, bf1);
    BAR();
    // ph4: (1,0); buf0-A dead after ph3 -> stage t+2:{B1,A0}
    if (full) {
      STAGE(0, 49152, pB0, pB1, kt + 128);
      STAGE(0, 0, pa0, pa1, kt + 128);
    }
    BAR();
    MFMA_Q(1, 0, bf0);
    if (full) WAITVM6(); else WAITVM0();  // tile 2it+1 fully landed
    BAR();
    // ph5: (0,0) of tile 2it+1 (buf1); stage t+2:A1
    LOAD_A(65536, 0);
    LOAD_B(65536, 0, bf0);
    if (full) STAGE(0, 16384, pA0, pA1, kt + 128);
    BAR();
    WAITLGKM();
    MFMA_Q(0, 0, bf0);
    BAR();
    // ph6: (0,1)
    LOAD_B(65536, 1, bf1);
    BAR();
    WAITLGKM();
    MFMA_Q(0, 1, bf1);
    BAR();
    // ph7: (1,1); stage t+3:B0
    LOAD_A(65536, 1);
    if (full) STAGE(65536, 32768, pb0, pb1, kt + 192);
    BAR();
    WAITLGKM();
    MFMA_Q(1, 1, bf1);
    BAR();
    // ph8: (1,0); stage t+3:{B1,A0}; vmcnt(6) lands tile 2it+2
    if (full) {
      STAGE(65536, 49152, pB0, pB1, kt + 192);
      STAGE(65536, 0, pa0, pa1, kt + 192);
    }
    BAR();
    MFMA_Q(1, 0, bf0);
    if (full) WAITVM6();
    BAR();
  }

  // epilogue: C/D layout col = lane&15, row = (lane>>4)*4 + reg.
  // Non-temporal: C is a 64MB fp32 stream; regular stores write-allocate in
  // L2/L3 and evict the (re-read) input panels -> HBM-latency staging stalls.
  const int orow = bm + wm * 128 + (kq << 2);
  const int ocol = bn + wn * 64 + l15;
#pragma unroll
  for (int m = 0; m < 8; ++m)
#pragma unroll
    for (int n = 0; n < 4; ++n)
#pragma unroll
      for (int r = 0; r < 4; ++r)
        __builtin_nontemporal_store(
            acc[m][n][r] * alpha,
            &C[(size_t)(orow + m * 16 + r) * N + (ocol + n * 16)]);
}

// fused fp32->fp16 cast of x (2M float4) and Wq|Wk|Wv (3M float4)
__global__ __launch_bounds__(256) void cast_all_kernel(
    const float* __restrict__ x, const float* __restrict__ wq,
    const float* __restrict__ wk, const float* __restrict__ wv,
    f16* __restrict__ xh, f16* __restrict__ wh) {
  int i = blockIdx.x * 256 + threadIdx.x;  // float4 index over 5M
  float4 v;
  f16x4* dst;
  if (i < 2097152) {
    v = reinterpret_cast<const float4*>(x)[i];
    dst = reinterpret_cast<f16x4*>(xh) + i;
  } else {
    int j = i - 2097152;
    int w = j >> 20, r = j & 1048575;
    const float* s = (w == 0) ? wq : (w == 1 ? wk : wv);
    v = reinterpret_cast<const float4*>(s)[r];
    dst = reinterpret_cast<f16x4*>(wh) + j;
  }
  *dst = f16x4{(f16)v.x, (f16)v.y, (f16)v.z, (f16)v.w};
}

// freqs[j] = 10000^(-j/1024); -log2(10000)/1024 = -0.012976281620653758
__global__ void freq_init_kernel(double* freqs) {
  int j = blockIdx.x * 256 + threadIdx.x;
  if (j < 1024) freqs[j] = exp2((double)j * -0.012976281620653758);
}

// RoPE over qk fp32 [S][4096] (cols 0..2047 = Q, 2048..4095 = K) -> f16.
__global__ __launch_bounds__(256) void rope_kernel(
    const float* __restrict__ qk, const double* __restrict__ freqs,
    f16* __restrict__ qr, f16* __restrict__ kr) {
  int idx = blockIdx.x * 256 + threadIdx.x;  // s*1024 + j
  int j = idx & 1023;
  int s = idx >> 10;
  double ang = (double)s * freqs[j];
  ang -= 6.2831853071795864769 * floor(ang * 0.15915494309189533577);
  float c, sn;
  sincosf((float)ang, &sn, &c);
  const float2* qp = reinterpret_cast<const float2*>(qk + (size_t)s * 4096);
  const float2* kp = reinterpret_cast<const float2*>(qk + (size_t)s * 4096 + 2048);
  float2 q2 = qp[j];
  float2 k2 = kp[j];
  f16x2 qo = {(f16)(q2.x * c - q2.y * sn), (f16)(q2.x * sn + q2.y * c)};
  f16x2 ko = {(f16)(k2.x * c - k2.y * sn), (f16)(k2.x * sn + k2.y * c)};
  reinterpret_cast<f16x2*>(qr)[idx] = qo;
  reinterpret_cast<f16x2*>(kr)[idx] = ko;
}

// V partial-reduce + transpose: vp = 2 x [S][2048] fp32 partials;
// vt[d][s] f16 = (f16)(vp0[s][d] + vp1[s][d]). grid (S/32, 2048/32), blk 32x8.
__global__ __launch_bounds__(256) void vredtranspose_kernel(
    const float* __restrict__ vp, f16* __restrict__ vt) {
  __shared__ float tile[32][33];
  const int sblk = blockIdx.x * 32, dblk = blockIdx.y * 32;
  const int tx = threadIdx.x, ty = threadIdx.y;  // 32 x 8
#pragma unroll
  for (int i = 0; i < 4; ++i) {
    const size_t idx = (size_t)(sblk + ty + i * 8) * 2048 + dblk + tx;
    tile[ty + i * 8][tx] = vp[idx] + vp[idx + 8388608];
  }
  __syncthreads();
#pragma unroll
  for (int i = 0; i < 4; ++i)
    vt[(size_t)(dblk + ty + i * 8) * 4096 + sblk + tx] =
        (f16)tile[tx][ty + i * 8];
}

__global__ __launch_bounds__(256) void softmax_kernel(
    float* __restrict__ sc, f16* __restrict__ wh) {
  const int row = blockIdx.x;
  float* p = sc + (size_t)row * 4096;
  const int tid = threadIdx.x;
  float4 v[4];
  float lmax = -3.0e38f;
#pragma unroll
  for (int i = 0; i < 4; ++i) {
    v[i] = reinterpret_cast<const float4*>(p)[tid + i * 256];
    lmax = fmaxf(lmax, fmaxf(fmaxf(v[i].x, v[i].y), fmaxf(v[i].z, v[i].w)));
  }
#pragma unroll
  for (int o = 32; o >= 1; o >>= 1) lmax = fmaxf(lmax, __shfl_xor(lmax, o));
  __shared__ float redm[4], reds[4];
  if ((tid & 63) == 0) redm[tid >> 6] = lmax;
  __syncthreads();
  const float gmax = fmaxf(fmaxf(redm[0], redm[1]), fmaxf(redm[2], redm[3]));
  float lsum = 0.f;
#pragma unroll
  for (int i = 0; i < 4; ++i) {
    v[i].x = expf(v[i].x - gmax);
    v[i].y = expf(v[i].y - gmax);
    v[i].z = expf(v[i].z - gmax);
    v[i].w = expf(v[i].w - gmax);
    lsum += (v[i].x + v[i].y) + (v[i].z + v[i].w);
  }
#pragma unroll
  for (int o = 32; o >= 1; o >>= 1) lsum += __shfl_xor(lsum, o);
  if ((tid & 63) == 0) reds[tid >> 6] = lsum;
  __syncthreads();
  const float inv = 1.0f / (reds[0] + reds[1] + reds[2] + reds[3]);
#pragma unroll
  for (int i = 0; i < 4; ++i) {
    float4 w4 = make_float4(v[i].x * inv, v[i].y * inv, v[i].z * inv, v[i].w * inv);
    reinterpret_cast<float4*>(p)[tid + i * 256] = w4;
    f16x4 h4 = {(f16)w4.x, (f16)w4.y, (f16)w4.z, (f16)w4.w};
    reinterpret_cast<f16x4*>(wh + (size_t)row * 4096)[tid + i * 256] = h4;
  }
}

// out = p[0..8M) + p[8M..16M), float4-vectorized (2M float4)
__global__ __launch_bounds__(256) void reduce2_kernel(
    const float* __restrict__ p, float* __restrict__ out) {
  int i = blockIdx.x * 256 + threadIdx.x;
  float4 a = reinterpret_cast<const float4*>(p)[i];
  float4 b = reinterpret_cast<const float4*>(p + 8388608)[i];
  reinterpret_cast<float4*>(out)[i] =
      make_float4(a.x + b.x, a.y + b.y, a.z + b.z, a.w + b.w);
}

extern "C" void kernel_launch(void* const* d_in, const int* in_sizes, int n_in,
                              void* d_out, int out_size, void* d_ws,
                              size_t ws_size, hipStream_t stream) {
  const int S = 4096, D = 2048;
  const float* x = (const float*)d_in[0];
  const float* Wq = (const float*)d_in[1];
  const float* Wk = (const float*)d_in[2];
  const float* Wv = (const float*)d_in[3];
  float* out = (float*)d_out;            // [S, D]
  float* weights = out + (size_t)S * D;  // [S, S]

  f16* x_h = (f16*)d_ws;                           // S*D f16 (16MB)
  f16* w_h = x_h + (size_t)S * D;                  // 3*D*D f16 (Wq|Wk|Wv rows)
  float* qk = (float*)(w_h + (size_t)3 * D * D);   // S x 4096 fp32 (64MB)
  float* vp = qk + (size_t)S * 4096;               // 2 x S*D fp32 V partials
  f16* qr = (f16*)(vp + (size_t)2 * S * D);        // S*D
  f16* kr = qr + (size_t)S * D;                    // S*D
  f16* vt = kr + (size_t)S * D;                    // D x S
  f16* wsm = vt + (size_t)S * D;                   // S*S
  double* freqs = (double*)(wsm + (size_t)S * S);  // 1024
  float* pvp = qk;  // PV partials (2 x S*D f32 = 67MB) reuse qk+vp (128MB)

  cast_all_kernel<<<20480, 256, 0, stream>>>(x, Wq, Wk, Wv, x_h, w_h);
  freq_init_kernel<<<4, 256, 0, stream>>>(freqs);

  // QK = x @ [Wq;Wk]^T : M=4096, N=4096, K=2048 -> 256 blocks, 1 round
  gemm256_8ph<<<dim3(16, 16, 1), 512, 0, stream>>>(x_h, w_h, qk, S, 2 * D, D,
                                                   D, 1.0f);
  // V = x @ Wv^T, split-K=2: M=4096, N=2048 -> 256 blocks, 1 round
  gemm256_8ph<<<dim3(8, 16, 2), 512, 0, stream>>>(
      x_h, w_h + (size_t)2 * D * D, vp, S, D, D / 2, D, 1.0f);

  rope_kernel<<<S * (D / 2) / 256, 256, 0, stream>>>(qk, freqs, qr, kr);
  vredtranspose_kernel<<<dim3(S / 32, D / 32), dim3(32, 8), 0, stream>>>(vp, vt);

  // scores = Q_rot @ K_rot^T / sqrt(D) -> 256 blocks, 1 round
  gemm256_8ph<<<dim3(16, 16, 1), 512, 0, stream>>>(qr, kr, weights, S, S, D, D,
                                                   0.02209708691207961f);
  softmax_kernel<<<S, 256, 0, stream>>>(weights, wsm);

  // output = wsm[S,S] @ vt[D,S]^T, split-K=2 -> 256 blocks, 1 round
  gemm256_8ph<<<dim3(8, 16, 2), 512, 0, stream>>>(wsm, vt, pvp, S, D, S / 2,
                                                  S, 1.0f);
  reduce2_kernel<<<8192, 256, 0, stream>>>(pvp, out);
}

// Round 12
// 318.501 us; speedup vs baseline: 1.1884x; 1.1884x over previous
//
#include <hip/hip_runtime.h>
#include <cmath>

// RoPEAttention: S=4096, D=2048, base=10000
// GEMM core (round-8 validated config, K-loop untouched): 256x256 tile,
// BK=64, 8 waves (2Mx4N), 8-phase schedule, counted vmcnt(6), XOR LDS
// swizzle (pre-swizzled source + swizzled ds_read, linear global_load_lds
// dest), s_setprio around MFMA. fp16 in, templated OutT out.
// All non-graded intermediates f16 (qk, V partials, scores, PV partials);
// graded outputs (weights, output) fp32. r11->r12: fixed softmax store bug
// (stray debug line zeroed half the fp32 weights lanes).
// NOTE (journal): T1 XCD swizzle regressed (L3-resident set); max-lead
// staging regressed (r9); NT C-stores regressed (r10); fused RoPE/V-epilogue
// deterministically corrupted (r4-6, suspected spill VMEM vs counted vmcnt).

typedef _Float16 f16;
typedef __attribute__((ext_vector_type(2))) _Float16 f16x2;
typedef __attribute__((ext_vector_type(4))) _Float16 f16x4;
typedef __attribute__((ext_vector_type(8))) _Float16 f16x8;
typedef __attribute__((ext_vector_type(4))) float f32x4;

#define GLD16(g, loff)                                                         \
  __builtin_amdgcn_global_load_lds(                                            \
      (const __attribute__((address_space(1))) void*)(g),                      \
      (__attribute__((address_space(3))) void*)(smem + (loff)), 16, 0, 0)

#define STAGE(BUFOFF, REG, PL0, PL1, KT)                                       \
  do {                                                                         \
    GLD16((PL0) + (KT), (BUFOFF) + (REG) + d0);                                \
    GLD16((PL1) + (KT), (BUFOFF) + (REG) + d1);                                \
  } while (0)

#define BAR() __builtin_amdgcn_s_barrier()
#define WAITVM6() asm volatile("s_waitcnt vmcnt(6)" ::: "memory")
#define WAITVM0() asm volatile("s_waitcnt vmcnt(0)" ::: "memory")

#define LOAD_A(BUF, MQ)                                                        \
  _Pragma("unroll") for (int i = 0; i < 4; ++i) {                              \
    af[i][0] = *(const f16x8*)(smem + (BUF) + rba +                            \
                               (((MQ) * 64 + i * 16) << 7) + kxa0);            \
    af[i][1] = *(const f16x8*)(smem + (BUF) + rba +                            \
                               (((MQ) * 64 + i * 16) << 7) + kxa1);            \
  }

#define LOAD_B(BUF, NQ, BF)                                                    \
  _Pragma("unroll") for (int j = 0; j < 2; ++j) {                              \
    BF[j][0] = *(const f16x8*)(smem + (BUF) + rbb +                            \
                               (((NQ) * 32 + j * 16) << 7) + kxa0);            \
    BF[j][1] = *(const f16x8*)(smem + (BUF) + rbb +                            \
                               (((NQ) * 32 + j * 16) << 7) + kxa1);            \
  }

#define MFMA_Q(MQ, NQ, BF)                                                     \
  __builtin_amdgcn_s_setprio(1);                                               \
  _Pragma("unroll") for (int ks = 0; ks < 2; ++ks)                             \
  _Pragma("unroll") for (int i = 0; i < 4; ++i)                                \
  _Pragma("unroll") for (int j = 0; j < 2; ++j)                                \
    acc[(MQ) * 4 + i][(NQ) * 2 + j] = __builtin_amdgcn_mfma_f32_16x16x32_f16(  \
        af[i][ks], BF[j][ks], acc[(MQ) * 4 + i][(NQ) * 2 + j], 0, 0, 0);       \
  __builtin_amdgcn_s_setprio(0)

// C[M,N] = alpha * A[M,K] @ B[N,K]^T, row stride Kstride for A and B.
// Split-K: blockIdx.z offsets A,B by z*K and C by z*M*N (partials).
// M,N % 256 == 0, K % 128 == 0. grid = (N/256, M/256, splits), block = 512.
template <typename OutT>
__global__ __launch_bounds__(512) void gemm256_8ph(
    const f16* __restrict__ A, const f16* __restrict__ B,
    OutT* __restrict__ C, int M, int N, int K, int Kstride, float alpha) {
  __shared__ __align__(16) char smem[131072];
  const int tid = threadIdx.x;
  const int wave = tid >> 6, lane = tid & 63;
  const int wm = wave >> 2, wn = wave & 3;  // 2 x 4 wave grid
  const int l15 = lane & 15, kq = lane >> 4;
  const int bm = blockIdx.y << 8, bn = blockIdx.x << 8;

  // split-K offsets (zero when gridDim.z == 1)
  const size_t zofs = (size_t)blockIdx.z * (size_t)K;
  A += zofs;
  B += zofs;
  C += (size_t)blockIdx.z * (size_t)M * N;

  f32x4 acc[8][4];
#pragma unroll
  for (int m = 0; m < 8; ++m)
#pragma unroll
    for (int n = 0; n < 4; ++n) acc[m][n] = f32x4{0.f, 0.f, 0.f, 0.f};

  // staging: half-tile = 1024 16B-chunks; chunk c -> (row=c>>3, slot=c&7);
  // source k8 = slot ^ (row&7)  (swizzle on the SOURCE, LDS dest linear).
  const int c0 = wave * 64 + lane;
  const int c1 = 512 + c0;
  const int r0 = c0 >> 3, q0 = ((c0 & 7) ^ (r0 & 7)) << 3;
  const int r1 = c1 >> 3, q1 = ((c1 & 7) ^ (r1 & 7)) << 3;
  const f16* pa0 = A + (size_t)(bm + r0) * Kstride + q0;        // A half0
  const f16* pa1 = A + (size_t)(bm + r1) * Kstride + q1;
  const f16* pA0 = A + (size_t)(bm + 128 + r0) * Kstride + q0;  // A half1
  const f16* pA1 = A + (size_t)(bm + 128 + r1) * Kstride + q1;
  const f16* pb0 = B + (size_t)(bn + r0) * Kstride + q0;        // B half0
  const f16* pb1 = B + (size_t)(bn + r1) * Kstride + q1;
  const f16* pB0 = B + (size_t)(bn + 128 + r0) * Kstride + q0;  // B half1
  const f16* pB1 = B + (size_t)(bn + 128 + r1) * Kstride + q1;
  const int d0 = wave << 10;
  const int d1 = 8192 + d0;

  // ds_read addressing (XOR swizzle on the read side)
  const int swz = l15 & 7;
  const int kxa0 = (kq ^ swz) << 4;
  const int kxa1 = ((4 + kq) ^ swz) << 4;
  const int rba = (wm * 128 + l15) << 7;
  const int rbb = 32768 + ((wn * 64 + l15) << 7);

  const int nt2 = K >> 7;  // each iteration covers 2 K-tiles of 64

  // prologue: t0 fully, t1 {B0,B1,A0}; vmcnt(6) lands t0.
  STAGE(0, 0, pa0, pa1, 0);
  STAGE(0, 16384, pA0, pA1, 0);
  STAGE(0, 32768, pb0, pb1, 0);
  STAGE(0, 49152, pB0, pB1, 0);
  STAGE(65536, 32768, pb0, pb1, 64);
  STAGE(65536, 49152, pB0, pB1, 64);
  STAGE(65536, 0, pa0, pa1, 64);
  WAITVM6();
  BAR();

  f16x8 af[4][2], bf0[2][2], bf1[2][2];

  for (int it = 0; it < nt2; ++it) {
    const int kt = it << 7;
    const bool full = (it != nt2 - 1);
    // ph1: quadrant (0,0) of tile 2it (buf0); stage t(2it+1):A1
    LOAD_A(0, 0);
    LOAD_B(0, 0, bf0);
    STAGE(65536, 16384, pA0, pA1, kt + 64);
    BAR();
    MFMA_Q(0, 0, bf0);
    BAR();
    // ph2: (0,1)
    LOAD_B(0, 1, bf1);
    BAR();
    MFMA_Q(0, 1, bf1);
    BAR();
    // ph3: (1,1); buf0-B dead after ph2 -> stage t+2:B0
    LOAD_A(0, 1);
    if (full) STAGE(0, 32768, pb0, pb1, kt + 128);
    BAR();
    MFMA_Q(1, 1, bf1);
    BAR();
    // ph4: (1,0); buf0-A dead after ph3 -> stage t+2:{B1,A0}
    if (full) {
      STAGE(0, 49152, pB0, pB1, kt + 128);
      STAGE(0, 0, pa0, pa1, kt + 128);
    }
    BAR();
    MFMA_Q(1, 0, bf0);
    if (full) WAITVM6(); else WAITVM0();  // tile 2it+1 fully landed
    BAR();
    // ph5: (0,0) of tile 2it+1 (buf1); stage t+2:A1
    LOAD_A(65536, 0);
    LOAD_B(65536, 0, bf0);
    if (full) STAGE(0, 16384, pA0, pA1, kt + 128);
    BAR();
    MFMA_Q(0, 0, bf0);
    BAR();
    // ph6: (0,1)
    LOAD_B(65536, 1, bf1);
    BAR();
    MFMA_Q(0, 1, bf1);
    BAR();
    // ph7: (1,1); stage t+3:B0
    LOAD_A(65536, 1);
    if (full) STAGE(65536, 32768, pb0, pb1, kt + 192);
    BAR();
    MFMA_Q(1, 1, bf1);
    BAR();
    // ph8: (1,0); stage t+3:{B1,A0}; vmcnt(6) lands tile 2it+2
    if (full) {
      STAGE(65536, 49152, pB0, pB1, kt + 192);
      STAGE(65536, 0, pa0, pa1, kt + 192);
    }
    BAR();
    MFMA_Q(1, 0, bf0);
    if (full) WAITVM6();
    BAR();
  }

  // epilogue: C/D layout col = lane&15, row = (lane>>4)*4 + reg
  const int orow = bm + wm * 128 + (kq << 2);
  const int ocol = bn + wn * 64 + l15;
#pragma unroll
  for (int m = 0; m < 8; ++m)
#pragma unroll
    for (int n = 0; n < 4; ++n)
#pragma unroll
      for (int r = 0; r < 4; ++r)
        C[(size_t)(orow + m * 16 + r) * N + (ocol + n * 16)] =
            (OutT)(acc[m][n][r] * alpha);
}

// fused fp32->fp16 cast of x (2M float4) and Wq|Wk|Wv (3M float4)
__global__ __launch_bounds__(256) void cast_all_kernel(
    const float* __restrict__ x, const float* __restrict__ wq,
    const float* __restrict__ wk, const float* __restrict__ wv,
    f16* __restrict__ xh, f16* __restrict__ wh) {
  int i = blockIdx.x * 256 + threadIdx.x;  // float4 index over 5M
  float4 v;
  f16x4* dst;
  if (i < 2097152) {
    v = reinterpret_cast<const float4*>(x)[i];
    dst = reinterpret_cast<f16x4*>(xh) + i;
  } else {
    int j = i - 2097152;
    int w = j >> 20, r = j & 1048575;
    const float* s = (w == 0) ? wq : (w == 1 ? wk : wv);
    v = reinterpret_cast<const float4*>(s)[r];
    dst = reinterpret_cast<f16x4*>(wh) + j;
  }
  *dst = f16x4{(f16)v.x, (f16)v.y, (f16)v.z, (f16)v.w};
}

// freqs[j] = 10000^(-j/1024); -log2(10000)/1024 = -0.012976281620653758
__global__ void freq_init_kernel(double* freqs) {
  int j = blockIdx.x * 256 + threadIdx.x;
  if (j < 1024) freqs[j] = exp2((double)j * -0.012976281620653758);
}

// RoPE over qk f16 [S][4096] (cols 0..2047 = Q, 2048..4095 = K) -> f16.
__global__ __launch_bounds__(256) void rope_kernel(
    const f16* __restrict__ qk, const double* __restrict__ freqs,
    f16* __restrict__ qr, f16* __restrict__ kr) {
  int idx = blockIdx.x * 256 + threadIdx.x;  // s*1024 + j
  int j = idx & 1023;
  int s = idx >> 10;
  double ang = (double)s * freqs[j];
  ang -= 6.2831853071795864769 * floor(ang * 0.15915494309189533577);
  float c, sn;
  sincosf((float)ang, &sn, &c);
  const f16x2* qp = reinterpret_cast<const f16x2*>(qk + (size_t)s * 4096);
  const f16x2* kp = reinterpret_cast<const f16x2*>(qk + (size_t)s * 4096 + 2048);
  f16x2 q2 = qp[j];
  f16x2 k2 = kp[j];
  const float qx = (float)q2[0], qy = (float)q2[1];
  const float kx = (float)k2[0], ky = (float)k2[1];
  f16x2 qo = {(f16)(qx * c - qy * sn), (f16)(qx * sn + qy * c)};
  f16x2 ko = {(f16)(kx * c - ky * sn), (f16)(kx * sn + ky * c)};
  reinterpret_cast<f16x2*>(qr)[idx] = qo;
  reinterpret_cast<f16x2*>(kr)[idx] = ko;
}

// V partial-reduce + transpose: vp = 2 x [S][2048] f16 partials;
// vt[d][s] f16 = (f16)((float)vp0[s][d] + (float)vp1[s][d]).
// grid (S/32, 2048/32), blk 32x8.
__global__ __launch_bounds__(256) void vredtranspose_kernel(
    const f16* __restrict__ vp, f16* __restrict__ vt) {
  __shared__ float tile[32][33];
  const int sblk = blockIdx.x * 32, dblk = blockIdx.y * 32;
  const int tx = threadIdx.x, ty = threadIdx.y;  // 32 x 8
#pragma unroll
  for (int i = 0; i < 4; ++i) {
    const size_t idx = (size_t)(sblk + ty + i * 8) * 2048 + dblk + tx;
    tile[ty + i * 8][tx] = (float)vp[idx] + (float)vp[idx + 8388608];
  }
  __syncthreads();
#pragma unroll
  for (int i = 0; i < 4; ++i)
    vt[(size_t)(dblk + ty + i * 8) * 4096 + sblk + tx] =
        (f16)tile[tx][ty + i * 8];
}

// Row softmax: read f16 scores [row][4096], write fp32 weights (graded)
// and f16 copy for the PV GEMM.
__global__ __launch_bounds__(256) void softmax_kernel(
    const f16* __restrict__ sc, float* __restrict__ weights,
    f16* __restrict__ wh) {
  const int row = blockIdx.x;
  const f16x8* p = reinterpret_cast<const f16x8*>(sc + (size_t)row * 4096);
  const int tid = threadIdx.x;
  float v[16];
  float lmax = -3.0e38f;
#pragma unroll
  for (int i = 0; i < 2; ++i) {
    f16x8 h = p[tid + i * 256];
#pragma unroll
    for (int t = 0; t < 8; ++t) {
      v[i * 8 + t] = (float)h[t];
      lmax = fmaxf(lmax, v[i * 8 + t]);
    }
  }
#pragma unroll
  for (int o = 32; o >= 1; o >>= 1) lmax = fmaxf(lmax, __shfl_xor(lmax, o));
  __shared__ float redm[4], reds[4];
  if ((tid & 63) == 0) redm[tid >> 6] = lmax;
  __syncthreads();
  const float gmax = fmaxf(fmaxf(redm[0], redm[1]), fmaxf(redm[2], redm[3]));
  float lsum = 0.f;
#pragma unroll
  for (int t = 0; t < 16; ++t) {
    v[t] = expf(v[t] - gmax);
    lsum += v[t];
  }
#pragma unroll
  for (int o = 32; o >= 1; o >>= 1) lsum += __shfl_xor(lsum, o);
  if ((tid & 63) == 0) reds[tid >> 6] = lsum;
  __syncthreads();
  const float inv = 1.0f / (reds[0] + reds[1] + reds[2] + reds[3]);
  float* wrow = weights + (size_t)row * 4096;
  f16* hrow = wh + (size_t)row * 4096;
#pragma unroll
  for (int i = 0; i < 2; ++i) {
    const int base = (tid + i * 256) * 8;
    float w[8];
    f16x8 h;
#pragma unroll
    for (int t = 0; t < 8; ++t) {
      w[t] = v[i * 8 + t] * inv;
      h[t] = (f16)w[t];
    }
    *reinterpret_cast<float4*>(wrow + base) =
        make_float4(w[0], w[1], w[2], w[3]);
    *reinterpret_cast<float4*>(wrow + base + 4) =
        make_float4(w[4], w[5], w[6], w[7]);
    *reinterpret_cast<f16x8*>(hrow + base) = h;
  }
}

// out(fp32) = (float)p[0..8M) + (float)p[8M..16M), f16x8-vectorized
__global__ __launch_bounds__(256) void reduce2_kernel(
    const f16* __restrict__ p, float* __restrict__ out) {
  int i = blockIdx.x * 256 + threadIdx.x;  // f16x8 unit over 1M
  f16x8 a = reinterpret_cast<const f16x8*>(p)[i];
  f16x8 b = reinterpret_cast<const f16x8*>(p + 8388608)[i];
  float4 o0, o1;
#pragma unroll
  for (int t = 0; t < 4; ++t) ((float*)&o0)[t] = (float)a[t] + (float)b[t];
#pragma unroll
  for (int t = 0; t < 4; ++t) ((float*)&o1)[t] = (float)a[4 + t] + (float)b[4 + t];
  reinterpret_cast<float4*>(out)[2 * i] = o0;
  reinterpret_cast<float4*>(out)[2 * i + 1] = o1;
}

extern "C" void kernel_launch(void* const* d_in, const int* in_sizes, int n_in,
                              void* d_out, int out_size, void* d_ws,
                              size_t ws_size, hipStream_t stream) {
  const int S = 4096, D = 2048;
  const float* x = (const float*)d_in[0];
  const float* Wq = (const float*)d_in[1];
  const float* Wk = (const float*)d_in[2];
  const float* Wv = (const float*)d_in[3];
  float* out = (float*)d_out;            // [S, D]
  float* weights = out + (size_t)S * D;  // [S, S]

  f16* x_h = (f16*)d_ws;                           // S*D f16 (16MB)
  f16* w_h = x_h + (size_t)S * D;                  // 3*D*D f16 (24MB)
  f16* qk_h = w_h + (size_t)3 * D * D;             // S x 4096 f16 (32MB)
  f16* vp_h = qk_h + (size_t)S * 4096;             // 2 x S*D f16 (32MB)
  f16* qr = vp_h + (size_t)2 * S * D;              // S*D (16MB)
  f16* kr = qr + (size_t)S * D;                    // S*D (16MB)
  f16* vt = kr + (size_t)S * D;                    // D x S (16MB)
  f16* wsm = vt + (size_t)S * D;                   // S*S (32MB)
  double* freqs = (double*)(wsm + (size_t)S * S);  // 1024
  f16* sch = vp_h;   // f16 scores scratch (32MB; vp dead after vred)
  f16* pvp_h = qk_h; // PV f16 partials (32MB; qk dead after rope)

  cast_all_kernel<<<20480, 256, 0, stream>>>(x, Wq, Wk, Wv, x_h, w_h);
  freq_init_kernel<<<4, 256, 0, stream>>>(freqs);

  // QK = x @ [Wq;Wk]^T -> f16: M=4096, N=4096, K=2048, 256 blocks
  gemm256_8ph<f16><<<dim3(16, 16, 1), 512, 0, stream>>>(
      x_h, w_h, qk_h, S, 2 * D, D, D, 1.0f);
  // V = x @ Wv^T, split-K=2 -> f16 partials: 256 blocks
  gemm256_8ph<f16><<<dim3(8, 16, 2), 512, 0, stream>>>(
      x_h, w_h + (size_t)2 * D * D, vp_h, S, D, D / 2, D, 1.0f);

  rope_kernel<<<S * (D / 2) / 256, 256, 0, stream>>>(qk_h, freqs, qr, kr);
  vredtranspose_kernel<<<dim3(S / 32, D / 32), dim3(32, 8), 0, stream>>>(vp_h, vt);

  // scores = Q_rot @ K_rot^T / sqrt(D) -> f16 scratch: 256 blocks
  gemm256_8ph<f16><<<dim3(16, 16, 1), 512, 0, stream>>>(
      qr, kr, sch, S, S, D, D, 0.02209708691207961f);
  softmax_kernel<<<S, 256, 0, stream>>>(sch, weights, wsm);

  // output = wsm[S,S] @ vt[D,S]^T, split-K=2 -> f16 partials: 256 blocks
  gemm256_8ph<f16><<<dim3(8, 16, 2), 512, 0, stream>>>(
      wsm, vt, pvp_h, S, D, S / 2, S, 1.0f);
  reduce2_kernel<<<4096, 256, 0, stream>>>(pvp_h, out);
}

// Round 13
// 314.152 us; speedup vs baseline: 1.2048x; 1.0138x over previous
//
#include <hip/hip_runtime.h>
#include <cmath>

// RoPEAttention: S=4096, D=2048, base=10000
// GEMM core: 256x256 tile, BK=64, 8 waves (2Mx4N), 8-phase schedule,
// counted vmcnt(6), XOR LDS swizzle, s_setprio around MFMA.
// r13: SINGLE barrier per phase (end only; was 2). The pre-MFMA barrier
// forced lockstep {all-read | all-MFMA} -> iter time = LDS + MFMA serial sum
// (~4.6k + ~5.0k cyc vs 10.3k observed). Removing it allows cross-wave
// LDS-read / MFMA overlap; correctness invariants (region-death vs STAGE,
// per-wave vmcnt counting, lgkm-before-own-MFMA) unchanged -- proof in
// journal. fp16 in, templated OutT out. Intermediates f16; graded fp32.
// NOTE (journal): T1 XCD swizzle regressed; max-lead staging regressed (r9);
// NT C-stores regressed (r10); fused RoPE/V epilogue corrupted (r4-6).

typedef _Float16 f16;
typedef __attribute__((ext_vector_type(2))) _Float16 f16x2;
typedef __attribute__((ext_vector_type(4))) _Float16 f16x4;
typedef __attribute__((ext_vector_type(8))) _Float16 f16x8;
typedef __attribute__((ext_vector_type(4))) float f32x4;

#define GLD16(g, loff)                                                         \
  __builtin_amdgcn_global_load_lds(                                            \
      (const __attribute__((address_space(1))) void*)(g),                      \
      (__attribute__((address_space(3))) void*)(smem + (loff)), 16, 0, 0)

#define STAGE(BUFOFF, REG, PL0, PL1, KT)                                       \
  do {                                                                         \
    GLD16((PL0) + (KT), (BUFOFF) + (REG) + d0);                                \
    GLD16((PL1) + (KT), (BUFOFF) + (REG) + d1);                                \
  } while (0)

#define BAR() __builtin_amdgcn_s_barrier()
#define WAITVM6() asm volatile("s_waitcnt vmcnt(6)" ::: "memory")
#define WAITVM0() asm volatile("s_waitcnt vmcnt(0)" ::: "memory")

#define LOAD_A(BUF, MQ)                                                        \
  _Pragma("unroll") for (int i = 0; i < 4; ++i) {                              \
    af[i][0] = *(const f16x8*)(smem + (BUF) + rba +                            \
                               (((MQ) * 64 + i * 16) << 7) + kxa0);            \
    af[i][1] = *(const f16x8*)(smem + (BUF) + rba +                            \
                               (((MQ) * 64 + i * 16) << 7) + kxa1);            \
  }

#define LOAD_B(BUF, NQ, BF)                                                    \
  _Pragma("unroll") for (int j = 0; j < 2; ++j) {                              \
    BF[j][0] = *(const f16x8*)(smem + (BUF) + rbb +                            \
                               (((NQ) * 32 + j * 16) << 7) + kxa0);            \
    BF[j][1] = *(const f16x8*)(smem + (BUF) + rbb +                            \
                               (((NQ) * 32 + j * 16) << 7) + kxa1);            \
  }

#define MFMA_Q(MQ, NQ, BF)                                                     \
  __builtin_amdgcn_s_setprio(1);                                               \
  _Pragma("unroll") for (int ks = 0; ks < 2; ++ks)                             \
  _Pragma("unroll") for (int i = 0; i < 4; ++i)                                \
  _Pragma("unroll") for (int j = 0; j < 2; ++j)                                \
    acc[(MQ) * 4 + i][(NQ) * 2 + j] = __builtin_amdgcn_mfma_f32_16x16x32_f16(  \
        af[i][ks], BF[j][ks], acc[(MQ) * 4 + i][(NQ) * 2 + j], 0, 0, 0);       \
  __builtin_amdgcn_s_setprio(0)

// C[M,N] = alpha * A[M,K] @ B[N,K]^T, row stride Kstride for A and B.
// Split-K: blockIdx.z offsets A,B by z*K and C by z*M*N (partials).
// M,N % 256 == 0, K % 128 == 0. grid = (N/256, M/256, splits), block = 512.
template <typename OutT>
__global__ __launch_bounds__(512) void gemm256_8ph(
    const f16* __restrict__ A, const f16* __restrict__ B,
    OutT* __restrict__ C, int M, int N, int K, int Kstride, float alpha) {
  __shared__ __align__(16) char smem[131072];
  const int tid = threadIdx.x;
  const int wave = tid >> 6, lane = tid & 63;
  const int wm = wave >> 2, wn = wave & 3;  // 2 x 4 wave grid
  const int l15 = lane & 15, kq = lane >> 4;
  const int bm = blockIdx.y << 8, bn = blockIdx.x << 8;

  // split-K offsets (zero when gridDim.z == 1)
  const size_t zofs = (size_t)blockIdx.z * (size_t)K;
  A += zofs;
  B += zofs;
  C += (size_t)blockIdx.z * (size_t)M * N;

  f32x4 acc[8][4];
#pragma unroll
  for (int m = 0; m < 8; ++m)
#pragma unroll
    for (int n = 0; n < 4; ++n) acc[m][n] = f32x4{0.f, 0.f, 0.f, 0.f};

  // staging: half-tile = 1024 16B-chunks; chunk c -> (row=c>>3, slot=c&7);
  // source k8 = slot ^ (row&7)  (swizzle on the SOURCE, LDS dest linear).
  const int c0 = wave * 64 + lane;
  const int c1 = 512 + c0;
  const int r0 = c0 >> 3, q0 = ((c0 & 7) ^ (r0 & 7)) << 3;
  const int r1 = c1 >> 3, q1 = ((c1 & 7) ^ (r1 & 7)) << 3;
  const f16* pa0 = A + (size_t)(bm + r0) * Kstride + q0;        // A half0
  const f16* pa1 = A + (size_t)(bm + r1) * Kstride + q1;
  const f16* pA0 = A + (size_t)(bm + 128 + r0) * Kstride + q0;  // A half1
  const f16* pA1 = A + (size_t)(bm + 128 + r1) * Kstride + q1;
  const f16* pb0 = B + (size_t)(bn + r0) * Kstride + q0;        // B half0
  const f16* pb1 = B + (size_t)(bn + r1) * Kstride + q1;
  const f16* pB0 = B + (size_t)(bn + 128 + r0) * Kstride + q0;  // B half1
  const f16* pB1 = B + (size_t)(bn + 128 + r1) * Kstride + q1;
  const int d0 = wave << 10;
  const int d1 = 8192 + d0;

  // ds_read addressing (XOR swizzle on the read side)
  const int swz = l15 & 7;
  const int kxa0 = (kq ^ swz) << 4;
  const int kxa1 = ((4 + kq) ^ swz) << 4;
  const int rba = (wm * 128 + l15) << 7;
  const int rbb = 32768 + ((wn * 64 + l15) << 7);

  const int nt2 = K >> 7;  // each iteration covers 2 K-tiles of 64

  // prologue: t0 fully, t1 {B0,B1,A0}; vmcnt(6) lands t0.
  STAGE(0, 0, pa0, pa1, 0);
  STAGE(0, 16384, pA0, pA1, 0);
  STAGE(0, 32768, pb0, pb1, 0);
  STAGE(0, 49152, pB0, pB1, 0);
  STAGE(65536, 32768, pb0, pb1, 64);
  STAGE(65536, 49152, pB0, pB1, 64);
  STAGE(65536, 0, pa0, pa1, 64);
  WAITVM6();
  BAR();

  f16x8 af[4][2], bf0[2][2], bf1[2][2];

  for (int it = 0; it < nt2; ++it) {
    const int kt = it << 7;
    const bool full = (it != nt2 - 1);
    // ph1: quadrant (0,0) of tile 2it (buf0); stage t(2it+1):A1.
    // Single barrier per phase (end only): waves overlap ds_read and MFMA.
    LOAD_A(0, 0);
    LOAD_B(0, 0, bf0);
    STAGE(65536, 16384, pA0, pA1, kt + 64);
    MFMA_Q(0, 0, bf0);
    BAR();
    // ph2: (0,1)
    LOAD_B(0, 1, bf1);
    MFMA_Q(0, 1, bf1);
    BAR();
    // ph3: (1,1); buf0-B dead after ph2 -> stage t+2:B0
    LOAD_A(0, 1);
    if (full) STAGE(0, 32768, pb0, pb1, kt + 128);
    MFMA_Q(1, 1, bf1);
    BAR();
    // ph4: (1,0); buf0-A dead after ph3 -> stage t+2:{B1,A0}
    if (full) {
      STAGE(0, 49152, pB0, pB1, kt + 128);
      STAGE(0, 0, pa0, pa1, kt + 128);
    }
    MFMA_Q(1, 0, bf0);
    if (full) WAITVM6(); else WAITVM0();  // tile 2it+1 fully landed
    BAR();
    // ph5: (0,0) of tile 2it+1 (buf1); stage t+2:A1
    LOAD_A(65536, 0);
    LOAD_B(65536, 0, bf0);
    if (full) STAGE(0, 16384, pA0, pA1, kt + 128);
    MFMA_Q(0, 0, bf0);
    BAR();
    // ph6: (0,1)
    LOAD_B(65536, 1, bf1);
    MFMA_Q(0, 1, bf1);
    BAR();
    // ph7: (1,1); stage t+3:B0
    LOAD_A(65536, 1);
    if (full) STAGE(65536, 32768, pb0, pb1, kt + 192);
    MFMA_Q(1, 1, bf1);
    BAR();
    // ph8: (1,0); stage t+3:{B1,A0}; vmcnt(6) lands tile 2it+2
    if (full) {
      STAGE(65536, 49152, pB0, pB1, kt + 192);
      STAGE(65536, 0, pa0, pa1, kt + 192);
    }
    MFMA_Q(1, 0, bf0);
    if (full) WAITVM6();
    BAR();
  }

  // epilogue: C/D layout col = lane&15, row = (lane>>4)*4 + reg
  const int orow = bm + wm * 128 + (kq << 2);
  const int ocol = bn + wn * 64 + l15;
#pragma unroll
  for (int m = 0; m < 8; ++m)
#pragma unroll
    for (int n = 0; n < 4; ++n)
#pragma unroll
      for (int r = 0; r < 4; ++r)
        C[(size_t)(orow + m * 16 + r) * N + (ocol + n * 16)] =
            (OutT)(acc[m][n][r] * alpha);
}

// fused fp32->fp16 cast of x (2M float4) and Wq|Wk|Wv (3M float4)
__global__ __launch_bounds__(256) void cast_all_kernel(
    const float* __restrict__ x, const float* __restrict__ wq,
    const float* __restrict__ wk, const float* __restrict__ wv,
    f16* __restrict__ xh, f16* __restrict__ wh) {
  int i = blockIdx.x * 256 + threadIdx.x;  // float4 index over 5M
  float4 v;
  f16x4* dst;
  if (i < 2097152) {
    v = reinterpret_cast<const float4*>(x)[i];
    dst = reinterpret_cast<f16x4*>(xh) + i;
  } else {
    int j = i - 2097152;
    int w = j >> 20, r = j & 1048575;
    const float* s = (w == 0) ? wq : (w == 1 ? wk : wv);
    v = reinterpret_cast<const float4*>(s)[r];
    dst = reinterpret_cast<f16x4*>(wh) + j;
  }
  *dst = f16x4{(f16)v.x, (f16)v.y, (f16)v.z, (f16)v.w};
}

// freqs[j] = 10000^(-j/1024); -log2(10000)/1024 = -0.012976281620653758
__global__ void freq_init_kernel(double* freqs) {
  int j = blockIdx.x * 256 + threadIdx.x;
  if (j < 1024) freqs[j] = exp2((double)j * -0.012976281620653758);
}

// RoPE over qk f16 [S][4096] (cols 0..2047 = Q, 2048..4095 = K) -> f16.
__global__ __launch_bounds__(256) void rope_kernel(
    const f16* __restrict__ qk, const double* __restrict__ freqs,
    f16* __restrict__ qr, f16* __restrict__ kr) {
  int idx = blockIdx.x * 256 + threadIdx.x;  // s*1024 + j
  int j = idx & 1023;
  int s = idx >> 10;
  double ang = (double)s * freqs[j];
  ang -= 6.2831853071795864769 * floor(ang * 0.15915494309189533577);
  float c, sn;
  sincosf((float)ang, &sn, &c);
  const f16x2* qp = reinterpret_cast<const f16x2*>(qk + (size_t)s * 4096);
  const f16x2* kp = reinterpret_cast<const f16x2*>(qk + (size_t)s * 4096 + 2048);
  f16x2 q2 = qp[j];
  f16x2 k2 = kp[j];
  const float qx = (float)q2[0], qy = (float)q2[1];
  const float kx = (float)k2[0], ky = (float)k2[1];
  f16x2 qo = {(f16)(qx * c - qy * sn), (f16)(qx * sn + qy * c)};
  f16x2 ko = {(f16)(kx * c - ky * sn), (f16)(kx * sn + ky * c)};
  reinterpret_cast<f16x2*>(qr)[idx] = qo;
  reinterpret_cast<f16x2*>(kr)[idx] = ko;
}

// V partial-reduce + transpose: vp = 2 x [S][2048] f16 partials;
// vt[d][s] f16 = (f16)((float)vp0[s][d] + (float)vp1[s][d]).
// grid (S/32, 2048/32), blk 32x8.
__global__ __launch_bounds__(256) void vredtranspose_kernel(
    const f16* __restrict__ vp, f16* __restrict__ vt) {
  __shared__ float tile[32][33];
  const int sblk = blockIdx.x * 32, dblk = blockIdx.y * 32;
  const int tx = threadIdx.x, ty = threadIdx.y;  // 32 x 8
#pragma unroll
  for (int i = 0; i < 4; ++i) {
    const size_t idx = (size_t)(sblk + ty + i * 8) * 2048 + dblk + tx;
    tile[ty + i * 8][tx] = (float)vp[idx] + (float)vp[idx + 8388608];
  }
  __syncthreads();
#pragma unroll
  for (int i = 0; i < 4; ++i)
    vt[(size_t)(dblk + ty + i * 8) * 4096 + sblk + tx] =
        (f16)tile[tx][ty + i * 8];
}

// Row softmax: read f16 scores [row][4096], write fp32 weights (graded)
// and f16 copy for the PV GEMM.
__global__ __launch_bounds__(256) void softmax_kernel(
    const f16* __restrict__ sc, float* __restrict__ weights,
    f16* __restrict__ wh) {
  const int row = blockIdx.x;
  const f16x8* p = reinterpret_cast<const f16x8*>(sc + (size_t)row * 4096);
  const int tid = threadIdx.x;
  float v[16];
  float lmax = -3.0e38f;
#pragma unroll
  for (int i = 0; i < 2; ++i) {
    f16x8 h = p[tid + i * 256];
#pragma unroll
    for (int t = 0; t < 8; ++t) {
      v[i * 8 + t] = (float)h[t];
      lmax = fmaxf(lmax, v[i * 8 + t]);
    }
  }
#pragma unroll
  for (int o = 32; o >= 1; o >>= 1) lmax = fmaxf(lmax, __shfl_xor(lmax, o));
  __shared__ float redm[4], reds[4];
  if ((tid & 63) == 0) redm[tid >> 6] = lmax;
  __syncthreads();
  const float gmax = fmaxf(fmaxf(redm[0], redm[1]), fmaxf(redm[2], redm[3]));
  float lsum = 0.f;
#pragma unroll
  for (int t = 0; t < 16; ++t) {
    v[t] = expf(v[t] - gmax);
    lsum += v[t];
  }
#pragma unroll
  for (int o = 32; o >= 1; o >>= 1) lsum += __shfl_xor(lsum, o);
  if ((tid & 63) == 0) reds[tid >> 6] = lsum;
  __syncthreads();
  const float inv = 1.0f / (reds[0] + reds[1] + reds[2] + reds[3]);
  float* wrow = weights + (size_t)row * 4096;
  f16* hrow = wh + (size_t)row * 4096;
#pragma unroll
  for (int i = 0; i < 2; ++i) {
    const int base = (tid + i * 256) * 8;
    float w[8];
    f16x8 h;
#pragma unroll
    for (int t = 0; t < 8; ++t) {
      w[t] = v[i * 8 + t] * inv;
      h[t] = (f16)w[t];
    }
    *reinterpret_cast<float4*>(wrow + base) =
        make_float4(w[0], w[1], w[2], w[3]);
    *reinterpret_cast<float4*>(wrow + base + 4) =
        make_float4(w[4], w[5], w[6], w[7]);
    *reinterpret_cast<f16x8*>(hrow + base) = h;
  }
}

// out(fp32) = (float)p[0..8M) + (float)p[8M..16M), f16x8-vectorized
__global__ __launch_bounds__(256) void reduce2_kernel(
    const f16* __restrict__ p, float* __restrict__ out) {
  int i = blockIdx.x * 256 + threadIdx.x;  // f16x8 unit over 1M
  f16x8 a = reinterpret_cast<const f16x8*>(p)[i];
  f16x8 b = reinterpret_cast<const f16x8*>(p + 8388608)[i];
  float4 o0, o1;
#pragma unroll
  for (int t = 0; t < 4; ++t) ((float*)&o0)[t] = (float)a[t] + (float)b[t];
#pragma unroll
  for (int t = 0; t < 4; ++t) ((float*)&o1)[t] = (float)a[4 + t] + (float)b[4 + t];
  reinterpret_cast<float4*>(out)[2 * i] = o0;
  reinterpret_cast<float4*>(out)[2 * i + 1] = o1;
}

extern "C" void kernel_launch(void* const* d_in, const int* in_sizes, int n_in,
                              void* d_out, int out_size, void* d_ws,
                              size_t ws_size, hipStream_t stream) {
  const int S = 4096, D = 2048;
  const float* x = (const float*)d_in[0];
  const float* Wq = (const float*)d_in[1];
  const float* Wk = (const float*)d_in[2];
  const float* Wv = (const float*)d_in[3];
  float* out = (float*)d_out;            // [S, D]
  float* weights = out + (size_t)S * D;  // [S, S]

  f16* x_h = (f16*)d_ws;                           // S*D f16 (16MB)
  f16* w_h = x_h + (size_t)S * D;                  // 3*D*D f16 (24MB)
  f16* qk_h = w_h + (size_t)3 * D * D;             // S x 4096 f16 (32MB)
  f16* vp_h = qk_h + (size_t)S * 4096;             // 2 x S*D f16 (32MB)
  f16* qr = vp_h + (size_t)2 * S * D;              // S*D (16MB)
  f16* kr = qr + (size_t)S * D;                    // S*D (16MB)
  f16* vt = kr + (size_t)S * D;                    // D x S (16MB)
  f16* wsm = vt + (size_t)S * D;                   // S*S (32MB)
  double* freqs = (double*)(wsm + (size_t)S * S);  // 1024
  f16* sch = vp_h;   // f16 scores scratch (32MB; vp dead after vred)
  f16* pvp_h = qk_h; // PV f16 partials (32MB; qk dead after rope)

  cast_all_kernel<<<20480, 256, 0, stream>>>(x, Wq, Wk, Wv, x_h, w_h);
  freq_init_kernel<<<4, 256, 0, stream>>>(freqs);

  // QK = x @ [Wq;Wk]^T -> f16: M=4096, N=4096, K=2048, 256 blocks
  gemm256_8ph<f16><<<dim3(16, 16, 1), 512, 0, stream>>>(
      x_h, w_h, qk_h, S, 2 * D, D, D, 1.0f);
  // V = x @ Wv^T, split-K=2 -> f16 partials: 256 blocks
  gemm256_8ph<f16><<<dim3(8, 16, 2), 512, 0, stream>>>(
      x_h, w_h + (size_t)2 * D * D, vp_h, S, D, D / 2, D, 1.0f);

  rope_kernel<<<S * (D / 2) / 256, 256, 0, stream>>>(qk_h, freqs, qr, kr);
  vredtranspose_kernel<<<dim3(S / 32, D / 32), dim3(32, 8), 0, stream>>>(vp_h, vt);

  // scores = Q_rot @ K_rot^T / sqrt(D) -> f16 scratch: 256 blocks
  gemm256_8ph<f16><<<dim3(16, 16, 1), 512, 0, stream>>>(
      qr, kr, sch, S, S, D, D, 0.02209708691207961f);
  softmax_kernel<<<S, 256, 0, stream>>>(sch, weights, wsm);

  // output = wsm[S,S] @ vt[D,S]^T, split-K=2 -> f16 partials: 256 blocks
  gemm256_8ph<f16><<<dim3(8, 16, 2), 512, 0, stream>>>(
      wsm, vt, pvp_h, S, D, S / 2, S, 1.0f);
  reduce2_kernel<<<4096, 256, 0, stream>>>(pvp_h, out);
}

// Round 14
// 308.339 us; speedup vs baseline: 1.2275x; 1.0189x over previous
//
#include <hip/hip_runtime.h>
#include <cmath>

// RoPEAttention: S=4096, D=2048, base=10000
// GEMM core: 256x256 tile, BK=64, 8 waves (2Mx4N), 8-phase schedule,
// counted vmcnt(6), XOR LDS swizzle, s_setprio around MFMA, single barrier
// per phase (r13). r14: read-hoisting for wave-local LDS/MFMA overlap --
// bf1 (q2 B-frags, disjoint regs) issued in ph1 before q1's MFMA; af reload
// for q3 placed after q2's MFMA issue (WAR program-ordered). Zero register
// delta (budget is full: 128 VGPR + 128 acc; extra sets would spill and
// poison the counted-vmcnt discipline). Intermediates f16; graded fp32.
// NOTE (journal): T1 XCD swizzle regressed; max-lead staging regressed (r9);
// NT C-stores regressed (r10); fused RoPE/V epilogue corrupted (r4-6).

typedef _Float16 f16;
typedef __attribute__((ext_vector_type(2))) _Float16 f16x2;
typedef __attribute__((ext_vector_type(4))) _Float16 f16x4;
typedef __attribute__((ext_vector_type(8))) _Float16 f16x8;
typedef __attribute__((ext_vector_type(4))) float f32x4;

#define GLD16(g, loff)                                                         \
  __builtin_amdgcn_global_load_lds(                                            \
      (const __attribute__((address_space(1))) void*)(g),                      \
      (__attribute__((address_space(3))) void*)(smem + (loff)), 16, 0, 0)

#define STAGE(BUFOFF, REG, PL0, PL1, KT)                                       \
  do {                                                                         \
    GLD16((PL0) + (KT), (BUFOFF) + (REG) + d0);                                \
    GLD16((PL1) + (KT), (BUFOFF) + (REG) + d1);                                \
  } while (0)

#define BAR() __builtin_amdgcn_s_barrier()
#define WAITVM6() asm volatile("s_waitcnt vmcnt(6)" ::: "memory")
#define WAITVM0() asm volatile("s_waitcnt vmcnt(0)" ::: "memory")

#define LOAD_A(BUF, MQ)                                                        \
  _Pragma("unroll") for (int i = 0; i < 4; ++i) {                              \
    af[i][0] = *(const f16x8*)(smem + (BUF) + rba +                            \
                               (((MQ) * 64 + i * 16) << 7) + kxa0);            \
    af[i][1] = *(const f16x8*)(smem + (BUF) + rba +                            \
                               (((MQ) * 64 + i * 16) << 7) + kxa1);            \
  }

#define LOAD_B(BUF, NQ, BF)                                                    \
  _Pragma("unroll") for (int j = 0; j < 2; ++j) {                              \
    BF[j][0] = *(const f16x8*)(smem + (BUF) + rbb +                            \
                               (((NQ) * 32 + j * 16) << 7) + kxa0);            \
    BF[j][1] = *(const f16x8*)(smem + (BUF) + rbb +                            \
                               (((NQ) * 32 + j * 16) << 7) + kxa1);            \
  }

#define MFMA_Q(MQ, NQ, BF)                                                     \
  __builtin_amdgcn_s_setprio(1);                                               \
  _Pragma("unroll") for (int ks = 0; ks < 2; ++ks)                             \
  _Pragma("unroll") for (int i = 0; i < 4; ++i)                                \
  _Pragma("unroll") for (int j = 0; j < 2; ++j)                                \
    acc[(MQ) * 4 + i][(NQ) * 2 + j] = __builtin_amdgcn_mfma_f32_16x16x32_f16(  \
        af[i][ks], BF[j][ks], acc[(MQ) * 4 + i][(NQ) * 2 + j], 0, 0, 0);       \
  __builtin_amdgcn_s_setprio(0)

// C[M,N] = alpha * A[M,K] @ B[N,K]^T, row stride Kstride for A and B.
// Split-K: blockIdx.z offsets A,B by z*K and C by z*M*N (partials).
// M,N % 256 == 0, K % 128 == 0. grid = (N/256, M/256, splits), block = 512.
template <typename OutT>
__global__ __launch_bounds__(512) void gemm256_8ph(
    const f16* __restrict__ A, const f16* __restrict__ B,
    OutT* __restrict__ C, int M, int N, int K, int Kstride, float alpha) {
  __shared__ __align__(16) char smem[131072];
  const int tid = threadIdx.x;
  const int wave = tid >> 6, lane = tid & 63;
  const int wm = wave >> 2, wn = wave & 3;  // 2 x 4 wave grid
  const int l15 = lane & 15, kq = lane >> 4;
  const int bm = blockIdx.y << 8, bn = blockIdx.x << 8;

  // split-K offsets (zero when gridDim.z == 1)
  const size_t zofs = (size_t)blockIdx.z * (size_t)K;
  A += zofs;
  B += zofs;
  C += (size_t)blockIdx.z * (size_t)M * N;

  f32x4 acc[8][4];
#pragma unroll
  for (int m = 0; m < 8; ++m)
#pragma unroll
    for (int n = 0; n < 4; ++n) acc[m][n] = f32x4{0.f, 0.f, 0.f, 0.f};

  // staging: half-tile = 1024 16B-chunks; chunk c -> (row=c>>3, slot=c&7);
  // source k8 = slot ^ (row&7)  (swizzle on the SOURCE, LDS dest linear).
  const int c0 = wave * 64 + lane;
  const int c1 = 512 + c0;
  const int r0 = c0 >> 3, q0 = ((c0 & 7) ^ (r0 & 7)) << 3;
  const int r1 = c1 >> 3, q1 = ((c1 & 7) ^ (r1 & 7)) << 3;
  const f16* pa0 = A + (size_t)(bm + r0) * Kstride + q0;        // A half0
  const f16* pa1 = A + (size_t)(bm + r1) * Kstride + q1;
  const f16* pA0 = A + (size_t)(bm + 128 + r0) * Kstride + q0;  // A half1
  const f16* pA1 = A + (size_t)(bm + 128 + r1) * Kstride + q1;
  const f16* pb0 = B + (size_t)(bn + r0) * Kstride + q0;        // B half0
  const f16* pb1 = B + (size_t)(bn + r1) * Kstride + q1;
  const f16* pB0 = B + (size_t)(bn + 128 + r0) * Kstride + q0;  // B half1
  const f16* pB1 = B + (size_t)(bn + 128 + r1) * Kstride + q1;
  const int d0 = wave << 10;
  const int d1 = 8192 + d0;

  // ds_read addressing (XOR swizzle on the read side)
  const int swz = l15 & 7;
  const int kxa0 = (kq ^ swz) << 4;
  const int kxa1 = ((4 + kq) ^ swz) << 4;
  const int rba = (wm * 128 + l15) << 7;
  const int rbb = 32768 + ((wn * 64 + l15) << 7);

  const int nt2 = K >> 7;  // each iteration covers 2 K-tiles of 64

  // prologue: t0 fully, t1 {B0,B1,A0}; vmcnt(6) lands t0.
  STAGE(0, 0, pa0, pa1, 0);
  STAGE(0, 16384, pA0, pA1, 0);
  STAGE(0, 32768, pb0, pb1, 0);
  STAGE(0, 49152, pB0, pB1, 0);
  STAGE(65536, 32768, pb0, pb1, 64);
  STAGE(65536, 49152, pB0, pB1, 64);
  STAGE(65536, 0, pa0, pa1, 64);
  WAITVM6();
  BAR();

  f16x8 af[4][2], bf0[2][2], bf1[2][2];

  for (int it = 0; it < nt2; ++it) {
    const int kt = it << 7;
    const bool full = (it != nt2 - 1);
    // ph1: reads for q1 AND q2 (bf1 hoisted -- its LDS service overlaps q1's
    // MFMA pipe time); stage t+1:A1; MFMA q1=(0,0).
    LOAD_A(0, 0);
    LOAD_B(0, 0, bf0);
    LOAD_B(0, 1, bf1);
    STAGE(65536, 16384, pA0, pA1, kt + 64);
    MFMA_Q(0, 0, bf0);
    BAR();
    // ph2: read-free MFMA q2=(0,1); af reload for q3 AFTER the MFMA issue
    // (WAR ordered) so the reads overlap the phase-end barrier wait.
    MFMA_Q(0, 1, bf1);
    LOAD_A(0, 1);
    BAR();
    // ph3: buf0-B dead after ph1 -> stage t+2:B0; MFMA q3=(1,1).
    if (full) STAGE(0, 32768, pb0, pb1, kt + 128);
    MFMA_Q(1, 1, bf1);
    BAR();
    // ph4: buf0-A dead after ph2 -> stage t+2:{B1,A0}; MFMA q4=(1,0).
    if (full) {
      STAGE(0, 49152, pB0, pB1, kt + 128);
      STAGE(0, 0, pa0, pa1, kt + 128);
    }
    MFMA_Q(1, 0, bf0);
    if (full) WAITVM6(); else WAITVM0();  // tile 2it+1 fully landed
    BAR();
    // ph5: (buf1) reads q1+q2; stage t+2:A1; MFMA q1.
    LOAD_A(65536, 0);
    LOAD_B(65536, 0, bf0);
    LOAD_B(65536, 1, bf1);
    if (full) STAGE(0, 16384, pA0, pA1, kt + 128);
    MFMA_Q(0, 0, bf0);
    BAR();
    // ph6: MFMA q2; af reload after issue.
    MFMA_Q(0, 1, bf1);
    LOAD_A(65536, 1);
    BAR();
    // ph7: stage t+3:B0; MFMA q3.
    if (full) STAGE(65536, 32768, pb0, pb1, kt + 192);
    MFMA_Q(1, 1, bf1);
    BAR();
    // ph8: stage t+3:{B1,A0}; MFMA q4; vmcnt(6) lands tile 2it+2.
    if (full) {
      STAGE(65536, 49152, pB0, pB1, kt + 192);
      STAGE(65536, 0, pa0, pa1, kt + 192);
    }
    MFMA_Q(1, 0, bf0);
    if (full) WAITVM6();
    BAR();
  }

  // epilogue: C/D layout col = lane&15, row = (lane>>4)*4 + reg
  const int orow = bm + wm * 128 + (kq << 2);
  const int ocol = bn + wn * 64 + l15;
#pragma unroll
  for (int m = 0; m < 8; ++m)
#pragma unroll
    for (int n = 0; n < 4; ++n)
#pragma unroll
      for (int r = 0; r < 4; ++r)
        C[(size_t)(orow + m * 16 + r) * N + (ocol + n * 16)] =
            (OutT)(acc[m][n][r] * alpha);
}

// fused fp32->fp16 cast of x (2M float4) + Wq|Wk|Wv (3M float4) + freq init
// (blocks 0..3: freqs[j] = 10000^(-j/1024); -log2(1e4)/1024 = -0.0129762816...)
__global__ __launch_bounds__(256) void cast_all_kernel(
    const float* __restrict__ x, const float* __restrict__ wq,
    const float* __restrict__ wk, const float* __restrict__ wv,
    f16* __restrict__ xh, f16* __restrict__ wh, double* __restrict__ freqs) {
  int i = blockIdx.x * 256 + threadIdx.x;  // float4 index over 5M
  if (i < 1024) freqs[i] = exp2((double)i * -0.012976281620653758);
  float4 v;
  f16x4* dst;
  if (i < 2097152) {
    v = reinterpret_cast<const float4*>(x)[i];
    dst = reinterpret_cast<f16x4*>(xh) + i;
  } else {
    int j = i - 2097152;
    int w = j >> 20, r = j & 1048575;
    const float* s = (w == 0) ? wq : (w == 1 ? wk : wv);
    v = reinterpret_cast<const float4*>(s)[r];
    dst = reinterpret_cast<f16x4*>(wh) + j;
  }
  *dst = f16x4{(f16)v.x, (f16)v.y, (f16)v.z, (f16)v.w};
}

// Merged RoPE (blocks 0..16383) + V partial-reduce/transpose (rest).
// rope: qk f16 [S][4096] (cols 0..2047=Q, 2048..4095=K) -> qr, kr f16.
// vred: vp = 2 x [S][2048] f16 partials -> vt[d][s] f16.
__global__ __launch_bounds__(256) void rope_vred_kernel(
    const f16* __restrict__ qk, const double* __restrict__ freqs,
    f16* __restrict__ qr, f16* __restrict__ kr,
    const f16* __restrict__ vp, f16* __restrict__ vt) {
  __shared__ float tile[32][33];
  const int bid = blockIdx.x;
  if (bid < 16384) {
    int idx = bid * 256 + threadIdx.x;  // s*1024 + j
    int j = idx & 1023;
    int s = idx >> 10;
    double ang = (double)s * freqs[j];
    ang -= 6.2831853071795864769 * floor(ang * 0.15915494309189533577);
    float c, sn;
    sincosf((float)ang, &sn, &c);
    const f16x2* qp = reinterpret_cast<const f16x2*>(qk + (size_t)s * 4096);
    const f16x2* kp =
        reinterpret_cast<const f16x2*>(qk + (size_t)s * 4096 + 2048);
    f16x2 q2 = qp[j];
    f16x2 k2 = kp[j];
    const float qx = (float)q2[0], qy = (float)q2[1];
    const float kx = (float)k2[0], ky = (float)k2[1];
    f16x2 qo = {(f16)(qx * c - qy * sn), (f16)(qx * sn + qy * c)};
    f16x2 ko = {(f16)(kx * c - ky * sn), (f16)(kx * sn + ky * c)};
    reinterpret_cast<f16x2*>(qr)[idx] = qo;
    reinterpret_cast<f16x2*>(kr)[idx] = ko;
  } else {
    const int vb = bid - 16384;            // 0..8191 = 128 x 64
    const int sblk = (vb & 127) * 32, dblk = (vb >> 7) * 32;
    const int tx = threadIdx.x & 31, ty = threadIdx.x >> 5;  // 32 x 8
#pragma unroll
    for (int i = 0; i < 4; ++i) {
      const size_t idx = (size_t)(sblk + ty + i * 8) * 2048 + dblk + tx;
      tile[ty + i * 8][tx] = (float)vp[idx] + (float)vp[idx + 8388608];
    }
    __syncthreads();
#pragma unroll
    for (int i = 0; i < 4; ++i)
      vt[(size_t)(dblk + ty + i * 8) * 4096 + sblk + tx] =
          (f16)tile[tx][ty + i * 8];
  }
}

// Row softmax: read f16 scores [row][4096], write fp32 weights (graded)
// and f16 copy for the PV GEMM.
__global__ __launch_bounds__(256) void softmax_kernel(
    const f16* __restrict__ sc, float* __restrict__ weights,
    f16* __restrict__ wh) {
  const int row = blockIdx.x;
  const f16x8* p = reinterpret_cast<const f16x8*>(sc + (size_t)row * 4096);
  const int tid = threadIdx.x;
  float v[16];
  float lmax = -3.0e38f;
#pragma unroll
  for (int i = 0; i < 2; ++i) {
    f16x8 h = p[tid + i * 256];
#pragma unroll
    for (int t = 0; t < 8; ++t) {
      v[i * 8 + t] = (float)h[t];
      lmax = fmaxf(lmax, v[i * 8 + t]);
    }
  }
#pragma unroll
  for (int o = 32; o >= 1; o >>= 1) lmax = fmaxf(lmax, __shfl_xor(lmax, o));
  __shared__ float redm[4], reds[4];
  if ((tid & 63) == 0) redm[tid >> 6] = lmax;
  __syncthreads();
  const float gmax = fmaxf(fmaxf(redm[0], redm[1]), fmaxf(redm[2], redm[3]));
  float lsum = 0.f;
#pragma unroll
  for (int t = 0; t < 16; ++t) {
    v[t] = expf(v[t] - gmax);
    lsum += v[t];
  }
#pragma unroll
  for (int o = 32; o >= 1; o >>= 1) lsum += __shfl_xor(lsum, o);
  if ((tid & 63) == 0) reds[tid >> 6] = lsum;
  __syncthreads();
  const float inv = 1.0f / (reds[0] + reds[1] + reds[2] + reds[3]);
  float* wrow = weights + (size_t)row * 4096;
  f16* hrow = wh + (size_t)row * 4096;
#pragma unroll
  for (int i = 0; i < 2; ++i) {
    const int base = (tid + i * 256) * 8;
    float w[8];
    f16x8 h;
#pragma unroll
    for (int t = 0; t < 8; ++t) {
      w[t] = v[i * 8 + t] * inv;
      h[t] = (f16)w[t];
    }
    *reinterpret_cast<float4*>(wrow + base) =
        make_float4(w[0], w[1], w[2], w[3]);
    *reinterpret_cast<float4*>(wrow + base + 4) =
        make_float4(w[4], w[5], w[6], w[7]);
    *reinterpret_cast<f16x8*>(hrow + base) = h;
  }
}

// out(fp32) = (float)p[0..8M) + (float)p[8M..16M), f16x8-vectorized
__global__ __launch_bounds__(256) void reduce2_kernel(
    const f16* __restrict__ p, float* __restrict__ out) {
  int i = blockIdx.x * 256 + threadIdx.x;  // f16x8 unit over 1M
  f16x8 a = reinterpret_cast<const f16x8*>(p)[i];
  f16x8 b = reinterpret_cast<const f16x8*>(p + 8388608)[i];
  float4 o0, o1;
#pragma unroll
  for (int t = 0; t < 4; ++t) ((float*)&o0)[t] = (float)a[t] + (float)b[t];
#pragma unroll
  for (int t = 0; t < 4; ++t) ((float*)&o1)[t] = (float)a[4 + t] + (float)b[4 + t];
  reinterpret_cast<float4*>(out)[2 * i] = o0;
  reinterpret_cast<float4*>(out)[2 * i + 1] = o1;
}

extern "C" void kernel_launch(void* const* d_in, const int* in_sizes, int n_in,
                              void* d_out, int out_size, void* d_ws,
                              size_t ws_size, hipStream_t stream) {
  const int S = 4096, D = 2048;
  const float* x = (const float*)d_in[0];
  const float* Wq = (const float*)d_in[1];
  const float* Wk = (const float*)d_in[2];
  const float* Wv = (const float*)d_in[3];
  float* out = (float*)d_out;            // [S, D]
  float* weights = out + (size_t)S * D;  // [S, S]

  f16* x_h = (f16*)d_ws;                           // S*D f16 (16MB)
  f16* w_h = x_h + (size_t)S * D;                  // 3*D*D f16 (24MB)
  f16* qk_h = w_h + (size_t)3 * D * D;             // S x 4096 f16 (32MB)
  f16* vp_h = qk_h + (size_t)S * 4096;             // 2 x S*D f16 (32MB)
  f16* qr = vp_h + (size_t)2 * S * D;              // S*D (16MB)
  f16* kr = qr + (size_t)S * D;                    // S*D (16MB)
  f16* vt = kr + (size_t)S * D;                    // D x S (16MB)
  f16* wsm = vt + (size_t)S * D;                   // S*S (32MB)
  double* freqs = (double*)(wsm + (size_t)S * S);  // 1024
  f16* sch = vp_h;   // f16 scores scratch (32MB; vp dead after vred)
  f16* pvp_h = qk_h; // PV f16 partials (32MB; qk dead after rope)

  cast_all_kernel<<<20480, 256, 0, stream>>>(x, Wq, Wk, Wv, x_h, w_h, freqs);

  // QK = x @ [Wq;Wk]^T -> f16: M=4096, N=4096, K=2048, 256 blocks
  gemm256_8ph<f16><<<dim3(16, 16, 1), 512, 0, stream>>>(
      x_h, w_h, qk_h, S, 2 * D, D, D, 1.0f);
  // V = x @ Wv^T, split-K=2 -> f16 partials: 256 blocks
  gemm256_8ph<f16><<<dim3(8, 16, 2), 512, 0, stream>>>(
      x_h, w_h + (size_t)2 * D * D, vp_h, S, D, D / 2, D, 1.0f);

  // RoPE (16384 blocks) + V reduce/transpose (8192 blocks), one launch
  rope_vred_kernel<<<24576, 256, 0, stream>>>(qk_h, freqs, qr, kr, vp_h, vt);

  // scores = Q_rot @ K_rot^T / sqrt(D) -> f16 scratch: 256 blocks
  gemm256_8ph<f16><<<dim3(16, 16, 1), 512, 0, stream>>>(
      qr, kr, sch, S, S, D, D, 0.02209708691207961f);
  softmax_kernel<<<S, 256, 0, stream>>>(sch, weights, wsm);

  // output = wsm[S,S] @ vt[D,S]^T, split-K=2 -> f16 partials: 256 blocks
  gemm256_8ph<f16><<<dim3(8, 16, 2), 512, 0, stream>>>(
      wsm, vt, pvp_h, S, D, S / 2, S, 1.0f);
  reduce2_kernel<<<4096, 256, 0, stream>>>(pvp_h, out);
}